// Round 14
// baseline (482.481 us; speedup 1.0000x reference)
//
#include <hip/hip_runtime.h>

typedef __attribute__((ext_vector_type(8)))  short s8b;    // 8 x bf16
typedef __attribute__((ext_vector_type(16))) float f32x16; // mfma C/D
typedef __attribute__((ext_vector_type(4)))  uint  uint4v;
typedef __attribute__((ext_vector_type(2)))  float float2v;
typedef __attribute__((ext_vector_type(4)))  float float4v;
typedef uint __attribute__((may_alias)) uint_ma;

static constexpr int   kBatch    = 2097152;
static constexpr float kActScale = 1.0f / 12.0f;
static constexpr float kAct2     = 1.0f / 6.0f;   // 2*ACT_SCALE

// fp32 table: [0,32) aout ; [32] cref
__device__ float g_tab[40];
// Weight A-frag tables, per matvec m: lane l holds W_m[row=l&31][j=16c+8*(l>>5)+b]
// m: 0=A0, 1=A1, 2=A1^T, 3=A0^T ; hl: 0=hi,1=lo ; c: k-chunk
__device__ __attribute__((aligned(16))) ushort g_wt[4][2][2][64][8];

__device__ __forceinline__ float rcp_f(float x) { return __fdividef(1.0f, x); }
__device__ __forceinline__ float sp_only(float x) {
    float e = __expf(-fabsf(x));
    return fmaxf(x, 0.0f) + __logf(1.0f + e);
}
__device__ __forceinline__ float sig_only(float x) {
    float e = __expf(-fabsf(x));
    float r = rcp_f(1.0f + e);
    return (x >= 0.0f) ? r : e * r;
}
__device__ __forceinline__ float sp_sig(float x, float& sig) {
    float e  = __expf(-fabsf(x));
    float oe = 1.0f + e;
    float r  = rcp_f(oe);
    sig = (x >= 0.0f) ? r : e * r;
    return fmaxf(x, 0.0f) + __logf(oe);
}

__device__ __forceinline__ uint  bf16u(float x) {
    uint u = __float_as_uint(x);
    return (u + 0x7FFFu + ((u >> 16) & 1u)) >> 16;      // RNE
}
__device__ __forceinline__ float bf16f(uint h) { return __uint_as_float(h << 16); }
__device__ __forceinline__ uint cvt_pk_bf16(float lo, float hi) {
    uint r;
    asm("v_cvt_pk_bf16_f32 %0, %1, %2" : "=v"(r) : "v"(lo), "v"(hi));
    return r;
}

// ---------------- prep: A-frag weight tables + aout + cref -------------------
__global__ __launch_bounds__(256) void icnn_prep(
    const float* __restrict__ rawA0, const float* __restrict__ rawA1,
    const float* __restrict__ rawAout,
    const float* __restrict__ W1,  const float* __restrict__ b1,
    const float* __restrict__ Wc0, const float* __restrict__ bc0,
    const float* __restrict__ Wc1, const float* __restrict__ bc1,
    const float* __restrict__ wout)
{
    __shared__ float sA0[1024], sA1[1024], sAout[32];
    const int t = threadIdx.x;
    for (int k = t; k < 1024; k += 256) sA0[k] = sp_only(rawA0[k]);
    for (int k = t; k < 1024; k += 256) sA1[k] = sp_only(rawA1[k]);
    if (t < 32) { float v = sp_only(rawAout[t]); sAout[t] = v; g_tab[t] = v; }
    __syncthreads();

    // A-frag tables: element (m, hl, c, l, b) = W_m[l&31][16c + 8*(l>>5) + b]
    for (int k = t; k < 8192; k += 256) {
        int m = k >> 11, r = k & 2047;
        int hl = r >> 10, c = (r >> 9) & 1, l = (r >> 3) & 63, b = r & 7;
        int row = l & 31, j = 16 * c + 8 * (l >> 5) + b;
        float v;
        if      (m == 0) v = sA0[row * 32 + j];
        else if (m == 1) v = sA1[row * 32 + j];
        else if (m == 2) v = sA1[j * 32 + row];     // A1^T
        else             v = sA0[j * 32 + row];     // A0^T
        uint hi = bf16u(v);
        g_wt[m][hl][c][l][b] = (ushort)(hl == 0 ? hi : bf16u(v - bf16f(hi)));
    }

    // cref: exact fp32 gradient dW/dI1 at z0 = 0 (wave-0 lanes 0..31)
    if (t < 32) {
        const int i = t;
        float sa, sc0v;
        float zi = sp_sig(b1[i], sa);
        float u = 0.0f;
        for (int j = 0; j < 32; j++) u = fmaf(sA0[i * 32 + j], __shfl(zi, j, 64), u);
        float su; float t0 = sp_sig(u, su);
        float d0 = kAct2 * t0 * su;
        float spc = sp_sig(bc0[i], sc0v);
        float zn = fmaf(kActScale * t0, t0, spc);
        float u1 = 0.0f;
        for (int j = 0; j < 32; j++) u1 = fmaf(sA1[i * 32 + j], __shfl(zn, j, 64), u1);
        float su1; float t1 = sp_sig(u1, su1);
        float d1 = sAout[i] * kAct2 * t1 * su1;
        float contrib = Wc1[2 * i] * sAout[i] * sig_only(bc1[i]);
        float g = 0.0f;
        for (int j = 0; j < 32; j++) g = fmaf(sA1[j * 32 + i], __shfl(d1, j, 64), g);
        contrib = fmaf(Wc0[2 * i], g * sc0v, contrib);
        float gu0 = g * d0;
        float ga = 0.0f;
        for (int j = 0; j < 32; j++) ga = fmaf(sA0[j * 32 + i], __shfl(gu0, j, 64), ga);
        ga *= sa;
        contrib = fmaf(W1[2 * i], ga, contrib);
        for (int off = 16; off >= 1; off >>= 1)
            contrib += __shfl_down(contrib, off, 32);
        if (i == 0) g_tab[32] = wout[0] + contrib;
    }
}

// weight A-frag load (pure SSA, 16B aligned)
__device__ __forceinline__ s8b ldwt(int m, int hl, int c, int lane) {
    const uint_ma* p = (const uint_ma*)&g_wt[m][hl][c][lane][0];
    uint4v q; q.x = p[0]; q.y = p[1]; q.z = p[2]; q.w = p[3];
    return __builtin_bit_cast(s8b, q);
}

// i-offset of C-frag element e (i = 4*half + OFF(e))
#define OFF(e) (((e) & 3) + 8 * ((e) >> 2))

// cross-half exchange: packed pair dwords PZ[0..7] (PZ[q] = units (4h+OFF(2q), +1))
// -> B-frags FA (k=0..15) and FB (k=16..31)
#define SXU(v) ((uint)__shfl_xor((int)(v), 32, 64))
#define SWAPJ(PZ, FA, FB) { \
    uint a0 = SXU(PZ[0]), a1 = SXU(PZ[1]), a2 = SXU(PZ[2]), a3 = SXU(PZ[3]); \
    uint a4 = SXU(PZ[4]), a5 = SXU(PZ[5]), a6 = SXU(PZ[6]), a7 = SXU(PZ[7]); \
    uint4v qa, qb; \
    qa.x = hb_ ? a2 : PZ[0]; qa.y = hb_ ? a3 : PZ[1]; \
    qa.z = hb_ ? PZ[2] : a0; qa.w = hb_ ? PZ[3] : a1; \
    qb.x = hb_ ? a6 : PZ[4]; qb.y = hb_ ? a7 : PZ[5]; \
    qb.z = hb_ ? PZ[6] : a4; qb.w = hb_ ? PZ[7] : a5; \
    FA = __builtin_bit_cast(s8b, qa); FB = __builtin_bit_cast(s8b, qb); }

// 4-mfma matvec: acc += (Whi + Wlo) x B, K=32 via 2 chained chunks
#define MM(m, BA, BB, ACC) { \
    ACC = __builtin_amdgcn_mfma_f32_32x32x16_bf16(ldwt(m, 0, 0, lane), BA, ACC, 0, 0, 0); \
    ACC = __builtin_amdgcn_mfma_f32_32x32x16_bf16(ldwt(m, 0, 1, lane), BB, ACC, 0, 0, 0); \
    ACC = __builtin_amdgcn_mfma_f32_32x32x16_bf16(ldwt(m, 1, 0, lane), BA, ACC, 0, 0, 0); \
    ACC = __builtin_amdgcn_mfma_f32_32x32x16_bf16(ldwt(m, 1, 1, lane), BB, ACC, 0, 0, 0); }

// ---------------- main: weights-as-A MFMA, zero LDS, 2 tile passes -----------
// C-frag: lane l holds C[i = 4*(l>>5)+OFF(e)][batch row = l&31] -- each lane
// owns 16 UNITS of ONE row => folds/activations are row-local; junction
// relayout = 8x shfl_xor(32) + 8 cndmask (SWAPJ), no LDS anywhere.
__global__ __launch_bounds__(256) void icnn_main(
    const float* __restrict__ eps,
    const float* __restrict__ W1,  const float* __restrict__ b1,
    const float* __restrict__ Wc0, const float* __restrict__ bc0,
    const float* __restrict__ Wc1, const float* __restrict__ bc1,
    const float* __restrict__ wout,
    float* __restrict__ out)
{
    const int tid  = threadIdx.x;
    const int lane = tid & 63;
    const bool hb_ = lane >= 32;
    const int  hB  = hb_ ? 1 : 0;            // half bit for addressing
    const long rowg = (long)blockIdx.x * 256 + tid;   // own row

    const float e11 = eps[rowg * 3 + 0];
    const float e22 = eps[rowg * 3 + 1];
    const float e12 = eps[rowg * 3 + 2];
    const float x1 = e11 + e22;
    const float x2 = e11 * e11 + 2.0f * e12 * e12 + e22 * e22;

    const float wout0 = wout[0], wout1 = wout[1];
    const float cref  = g_tab[32];
    const char* W1c  = (const char*)W1;
    const char* b1c  = (const char*)b1;
    const char* Wc0c = (const char*)Wc0;
    const char* bc0c = (const char*)bc0;
    const char* Wc1c = (const char*)Wc1;
    const char* bc1c = (const char*)bc1;
    const char* aoc  = (const char*)&g_tab[0];

    float dI1v[2], dI2v[2];

    #pragma unroll
    for (int pass = 0; pass < 2; ++pass) {
        // x of this pass's tile row (row-in-tile = lane&31)
        const float x1r = __shfl(x1, (lane & 31) + 32 * pass, 64);
        const float x2r = __shfl(x2, (lane & 31) + 32 * pass, 64);

        float g0p = 0.0f, gqp = 0.0f;

        // ---- Stage A: z B-frags computed directly (j = 16c + 8h + b)
        uint zf[2][4];
        #pragma unroll
        for (int c = 0; c < 2; ++c)
        #pragma unroll
        for (int s = 0; s < 4; ++s) {
            const float4v w4 = *(const float4v*)(W1c + 64 * hB + 128 * c + 16 * s);
            const float2v b2 = *(const float2v*)(b1c + 32 * hB + 64 * c + 8 * s);
            float a0 = fmaf(w4.x, x1r, fmaf(w4.y, x2r, b2.x));
            float a1 = fmaf(w4.z, x1r, fmaf(w4.w, x2r, b2.y));
            zf[c][s] = cvt_pk_bf16(sp_only(a0), sp_only(a1));
        }
        uint4v zq0, zq1;
        zq0.x = zf[0][0]; zq0.y = zf[0][1]; zq0.z = zf[0][2]; zq0.w = zf[0][3];
        zq1.x = zf[1][0]; zq1.y = zf[1][1]; zq1.z = zf[1][2]; zq1.w = zf[1][3];
        s8b fA = __builtin_bit_cast(s8b, zq0);
        s8b fB = __builtin_bit_cast(s8b, zq1);

        // ---- matvec 0: u0 = A0 z
        f32x16 acc = {};
        MM(0, fA, fB, acc)

        // ---- Stage B epilogue: d0 (packed), zn (packed, exact f32 c0)
        uint pd0[8], pz[8];
        #pragma unroll
        for (int q = 0; q < 8; ++q) {
            const int e = 2 * q, off = OFF(e);
            const float4v wc = *(const float4v*)(Wc0c + 32 * hB + 8 * off);
            const float2v bc = *(const float2v*)(bc0c + 16 * hB + 4 * off);
            float su;  float t  = sp_sig(acc[e], su);
            float su2; float t2 = sp_sig(acc[e + 1], su2);
            float c0a = fmaf(wc.x, x1r, fmaf(wc.y, x2r, bc.x));
            float c0b = fmaf(wc.z, x1r, fmaf(wc.w, x2r, bc.y));
            pd0[q] = cvt_pk_bf16(kAct2 * t * su, kAct2 * t2 * su2);
            pz[q]  = cvt_pk_bf16(fmaf(kActScale * t, t, sp_only(c0a)),
                                 fmaf(kActScale * t2, t2, sp_only(c0b)));
        }
        SWAPJ(pz, fA, fB)

        // ---- matvec 1: u1 = A1 zn
        f32x16 acc1 = {};
        MM(1, fA, fB, acc1)

        // ---- Stage C: T1 fold (c1-skip) + d1
        uint pdd[8];
        #pragma unroll
        for (int q = 0; q < 8; ++q) {
            const int e = 2 * q, off = OFF(e);
            const float4v wc = *(const float4v*)(Wc1c + 32 * hB + 8 * off);
            const float2v bc = *(const float2v*)(bc1c + 16 * hB + 4 * off);
            const float2v ao = *(const float2v*)(aoc  + 16 * hB + 4 * off);
            float c1a = fmaf(wc.x, x1r, fmaf(wc.y, x2r, bc.x));
            float c1b = fmaf(wc.z, x1r, fmaf(wc.w, x2r, bc.y));
            float wA = ao.x * sig_only(c1a);
            float wB = ao.y * sig_only(c1b);
            g0p = fmaf(wc.x, wA, g0p); gqp = fmaf(wc.y, wA, gqp);
            g0p = fmaf(wc.z, wB, g0p); gqp = fmaf(wc.w, wB, gqp);
            float su;  float t  = sp_sig(acc1[e], su);
            float su2; float t2 = sp_sig(acc1[e + 1], su2);
            pdd[q] = cvt_pk_bf16(ao.x * kAct2 * t * su, ao.y * kAct2 * t2 * su2);
        }
        SWAPJ(pdd, fA, fB)

        // ---- matvec 2: g = A1^T d1 (raw f32 in acc2)
        f32x16 acc2 = {};
        MM(2, fA, fB, acc2)

        // ---- T2 fold (c0-skip, reversed assoc) + gg = g*d0
        uint pgg[8];
        #pragma unroll
        for (int q = 0; q < 8; ++q) {
            const int e = 2 * q, off = OFF(e);
            const float4v wc = *(const float4v*)(Wc0c + 32 * hB + 8 * off);
            const float2v bc = *(const float2v*)(bc0c + 16 * hB + 4 * off);
            float c0a = fmaf(wc.y, x2r, fmaf(wc.x, x1r, bc.x));
            float c0b = fmaf(wc.w, x2r, fmaf(wc.z, x1r, bc.y));
            float tA = acc2[e]     * sig_only(c0a);
            float tB = acc2[e + 1] * sig_only(c0b);
            g0p = fmaf(wc.x, tA, g0p); gqp = fmaf(wc.y, tA, gqp);
            g0p = fmaf(wc.z, tB, g0p); gqp = fmaf(wc.w, tB, gqp);
            pgg[q] = cvt_pk_bf16(acc2[e] * bf16f(pd0[q] & 0xFFFFu),
                                 acc2[e + 1] * bf16f(pd0[q] >> 16));
        }
        SWAPJ(pgg, fA, fB)

        // ---- matvec 3: A0^T gg
        f32x16 acc3 = {};
        MM(3, fA, fB, acc3)

        // ---- T3 fold (first-layer, reversed assoc)
        #pragma unroll
        for (int q = 0; q < 8; ++q) {
            const int e = 2 * q, off = OFF(e);
            const float4v w4 = *(const float4v*)(W1c + 32 * hB + 8 * off);
            const float2v b2 = *(const float2v*)(b1c + 16 * hB + 4 * off);
            float aa = fmaf(w4.y, x2r, fmaf(w4.x, x1r, b2.x));
            float ab = fmaf(w4.w, x2r, fmaf(w4.z, x1r, b2.y));
            float gA = acc3[e]     * sig_only(aa);
            float gB = acc3[e + 1] * sig_only(ab);
            g0p = fmaf(w4.x, gA, g0p); gqp = fmaf(w4.y, gA, gqp);
            g0p = fmaf(w4.z, gB, g0p); gqp = fmaf(w4.w, gB, gqp);
        }

        // ---- cross-half reduce: each row's full sum = both halves' partials
        float g0f = wout0 + g0p + __shfl_xor(g0p, 32, 64);
        float gqf = wout1 + gqp + __shfl_xor(gqp, 32, 64);
        dI1v[pass] = g0f - cref;
        dI2v[pass] = gqf;
    }

    // own row (base + lane) was handled in pass = (lane>=32)
    const float dI1 = hb_ ? dI1v[1] : dI1v[0];
    const float dI2 = hb_ ? dI2v[1] : dI2v[0];
    out[rowg * 3 + 0] = fmaf(2.0f * e11, dI2, dI1);
    out[rowg * 3 + 1] = fmaf(2.0f * e22, dI2, dI1);
    out[rowg * 3 + 2] = 2.0f * e12 * dI2;
}

extern "C" void kernel_launch(void* const* d_in, const int* in_sizes, int n_in,
                              void* d_out, int out_size, void* d_ws, size_t ws_size,
                              hipStream_t stream)
{
    (void)in_sizes; (void)n_in; (void)out_size; (void)d_ws; (void)ws_size;
    const float* eps    = (const float*)d_in[0];
    const float* W1     = (const float*)d_in[1];
    const float* b1     = (const float*)d_in[2];
    const float* rawA0  = (const float*)d_in[3];
    const float* rawA1  = (const float*)d_in[4];
    const float* Wc0    = (const float*)d_in[5];
    const float* bc0    = (const float*)d_in[6];
    const float* Wc1    = (const float*)d_in[7];
    const float* bc1    = (const float*)d_in[8];
    const float* rawAout= (const float*)d_in[9];
    const float* wout   = (const float*)d_in[10];
    float* out = (float*)d_out;

    icnn_prep<<<1, 256, 0, stream>>>(rawA0, rawA1, rawAout, W1, b1, Wc0, bc0, Wc1, bc1, wout);
    icnn_main<<<kBatch / 256, 256, 0, stream>>>(eps, W1, b1, Wc0, bc0, Wc1, bc1, wout, out);
}

// Round 15
// 320.733 us; speedup vs baseline: 1.5043x; 1.5043x over previous
//
#include <hip/hip_runtime.h>

typedef __attribute__((ext_vector_type(8)))  short s8b;    // 8 x bf16
typedef __attribute__((ext_vector_type(16))) float f32x16; // mfma C/D
typedef __attribute__((ext_vector_type(4)))  uint  uint4v;
typedef __attribute__((ext_vector_type(2)))  float float2v;
typedef __attribute__((ext_vector_type(4)))  float float4v;
typedef uint __attribute__((may_alias)) uint_ma;

static constexpr int   kBatch    = 2097152;
static constexpr float kActScale = 1.0f / 12.0f;
static constexpr float kAct2     = 1.0f / 6.0f;   // 2*ACT_SCALE

// fp32 table: [0,32) aout ; [32] cref
__device__ float g_tab[40];
// Weight A-frag tables, per matvec m: lane l holds W_m[row=l&31][j=16c+8*(l>>5)+b]
// m: 0=A0, 1=A1, 2=A1^T, 3=A0^T ; hl: 0=hi,1=lo ; c: k-chunk
__device__ __attribute__((aligned(16))) ushort g_wt[4][2][2][64][8];

__device__ __forceinline__ float rcp_f(float x) { return __fdividef(1.0f, x); }
__device__ __forceinline__ float sp_only(float x) {
    float e = __expf(-fabsf(x));
    return fmaxf(x, 0.0f) + __logf(1.0f + e);
}
__device__ __forceinline__ float sig_only(float x) {
    float e = __expf(-fabsf(x));
    float r = rcp_f(1.0f + e);
    return (x >= 0.0f) ? r : e * r;
}
__device__ __forceinline__ float sp_sig(float x, float& sig) {
    float e  = __expf(-fabsf(x));
    float oe = 1.0f + e;
    float r  = rcp_f(oe);
    sig = (x >= 0.0f) ? r : e * r;
    return fmaxf(x, 0.0f) + __logf(oe);
}

__device__ __forceinline__ uint  bf16u(float x) {
    uint u = __float_as_uint(x);
    return (u + 0x7FFFu + ((u >> 16) & 1u)) >> 16;      // RNE
}
__device__ __forceinline__ float bf16f(uint h) { return __uint_as_float(h << 16); }
__device__ __forceinline__ uint cvt_pk_bf16(float lo, float hi) {
    uint r;
    asm("v_cvt_pk_bf16_f32 %0, %1, %2" : "=v"(r) : "v"(lo), "v"(hi));
    return r;
}

// ---------------- prep: A-frag weight tables + aout + cref -------------------
__global__ __launch_bounds__(256) void icnn_prep(
    const float* __restrict__ rawA0, const float* __restrict__ rawA1,
    const float* __restrict__ rawAout,
    const float* __restrict__ W1,  const float* __restrict__ b1,
    const float* __restrict__ Wc0, const float* __restrict__ bc0,
    const float* __restrict__ Wc1, const float* __restrict__ bc1,
    const float* __restrict__ wout)
{
    __shared__ float sA0[1024], sA1[1024], sAout[32];
    const int t = threadIdx.x;
    for (int k = t; k < 1024; k += 256) sA0[k] = sp_only(rawA0[k]);
    for (int k = t; k < 1024; k += 256) sA1[k] = sp_only(rawA1[k]);
    if (t < 32) { float v = sp_only(rawAout[t]); sAout[t] = v; g_tab[t] = v; }
    __syncthreads();

    // A-frag tables: element (m, hl, c, l, b) = W_m[l&31][16c + 8*(l>>5) + b]
    for (int k = t; k < 8192; k += 256) {
        int m = k >> 11, r = k & 2047;
        int hl = r >> 10, c = (r >> 9) & 1, l = (r >> 3) & 63, b = r & 7;
        int row = l & 31, j = 16 * c + 8 * (l >> 5) + b;
        float v;
        if      (m == 0) v = sA0[row * 32 + j];
        else if (m == 1) v = sA1[row * 32 + j];
        else if (m == 2) v = sA1[j * 32 + row];     // A1^T
        else             v = sA0[j * 32 + row];     // A0^T
        uint hi = bf16u(v);
        g_wt[m][hl][c][l][b] = (ushort)(hl == 0 ? hi : bf16u(v - bf16f(hi)));
    }

    // cref: exact fp32 gradient dW/dI1 at z0 = 0 (wave-0 lanes 0..31)
    if (t < 32) {
        const int i = t;
        float sa, sc0v;
        float zi = sp_sig(b1[i], sa);
        float u = 0.0f;
        for (int j = 0; j < 32; j++) u = fmaf(sA0[i * 32 + j], __shfl(zi, j, 64), u);
        float su; float t0 = sp_sig(u, su);
        float d0 = kAct2 * t0 * su;
        float spc = sp_sig(bc0[i], sc0v);
        float zn = fmaf(kActScale * t0, t0, spc);
        float u1 = 0.0f;
        for (int j = 0; j < 32; j++) u1 = fmaf(sA1[i * 32 + j], __shfl(zn, j, 64), u1);
        float su1; float t1 = sp_sig(u1, su1);
        float d1 = sAout[i] * kAct2 * t1 * su1;
        float contrib = Wc1[2 * i] * sAout[i] * sig_only(bc1[i]);
        float g = 0.0f;
        for (int j = 0; j < 32; j++) g = fmaf(sA1[j * 32 + i], __shfl(d1, j, 64), g);
        contrib = fmaf(Wc0[2 * i], g * sc0v, contrib);
        float gu0 = g * d0;
        float ga = 0.0f;
        for (int j = 0; j < 32; j++) ga = fmaf(sA0[j * 32 + i], __shfl(gu0, j, 64), ga);
        ga *= sa;
        contrib = fmaf(W1[2 * i], ga, contrib);
        for (int off = 16; off >= 1; off >>= 1)
            contrib += __shfl_down(contrib, off, 32);
        if (i == 0) g_tab[32] = wout[0] + contrib;
    }
}

// weight A-frag load (pure SSA, 16B aligned)
__device__ __forceinline__ s8b ldwt(int m, int hl, int c, int lane) {
    const uint_ma* p = (const uint_ma*)&g_wt[m][hl][c][lane][0];
    uint4v q; q.x = p[0]; q.y = p[1]; q.z = p[2]; q.w = p[3];
    return __builtin_bit_cast(s8b, q);
}

// i-offset of C-frag element e (i = 4*half + OFF(e))
#define OFF(e) (((e) & 3) + 8 * ((e) >> 2))

// cross-half exchange: packed pair dwords PZ[0..7] (PZ[q] = units (4h+OFF(2q), +1))
// -> B-frags FA (k=0..15) and FB (k=16..31)
#define SXU(v) ((uint)__shfl_xor((int)(v), 32, 64))
#define SWAPJ(PZ, FA, FB) { \
    uint a0 = SXU(PZ[0]), a1 = SXU(PZ[1]), a2 = SXU(PZ[2]), a3 = SXU(PZ[3]); \
    uint a4 = SXU(PZ[4]), a5 = SXU(PZ[5]), a6 = SXU(PZ[6]), a7 = SXU(PZ[7]); \
    uint4v qa, qb; \
    qa.x = hb_ ? a2 : PZ[0]; qa.y = hb_ ? a3 : PZ[1]; \
    qa.z = hb_ ? PZ[2] : a0; qa.w = hb_ ? PZ[3] : a1; \
    qb.x = hb_ ? a6 : PZ[4]; qb.y = hb_ ? a7 : PZ[5]; \
    qb.z = hb_ ? PZ[6] : a4; qb.w = hb_ ? PZ[7] : a5; \
    FA = __builtin_bit_cast(s8b, qa); FB = __builtin_bit_cast(s8b, qb); }

// 4-mfma matvec: acc += (Whi + Wlo) x B, K=32 via 2 chained chunks
#define MM(m, BA, BB, ACC) { \
    ACC = __builtin_amdgcn_mfma_f32_32x32x16_bf16(ldwt(m, 0, 0, lane), BA, ACC, 0, 0, 0); \
    ACC = __builtin_amdgcn_mfma_f32_32x32x16_bf16(ldwt(m, 0, 1, lane), BB, ACC, 0, 0, 0); \
    ACC = __builtin_amdgcn_mfma_f32_32x32x16_bf16(ldwt(m, 1, 0, lane), BA, ACC, 0, 0, 0); \
    ACC = __builtin_amdgcn_mfma_f32_32x32x16_bf16(ldwt(m, 1, 1, lane), BB, ACC, 0, 0, 0); }

// ---------------- main: weights-as-A MFMA, zero LDS, ONE 32-row tile/wave ----
// R14 post-mortem: 2 tile passes/wave -> 172 VGPR, 11.5% occupancy, latency-
// exposed. This round: one tile per wave (grid x2). Lane l's assigned row =
// lane&31 = the row whose eps it loaded -> x1/x2 are OWN registers (no
// shuffles); halves l and l+32 split the unit dimension (hB) and their fold
// partials combine with one shfl_xor(32) at the end. Peak live ~90 regs.
__global__ __launch_bounds__(256) void icnn_main(
    const float* __restrict__ eps,
    const float* __restrict__ W1,  const float* __restrict__ b1,
    const float* __restrict__ Wc0, const float* __restrict__ bc0,
    const float* __restrict__ Wc1, const float* __restrict__ bc1,
    const float* __restrict__ wout,
    float* __restrict__ out)
{
    const int tid  = threadIdx.x;
    const int lane = tid & 63, wib = tid >> 6;
    const bool hb_ = lane >= 32;
    const int  hB  = hb_ ? 1 : 0;
    const int  rowl = lane & 31;
    const long rowg = ((long)blockIdx.x * 4 + wib) * 32 + rowl;

    const float e11 = eps[rowg * 3 + 0];
    const float e22 = eps[rowg * 3 + 1];
    const float e12 = eps[rowg * 3 + 2];
    const float x1 = e11 + e22;
    const float x2 = e11 * e11 + 2.0f * e12 * e12 + e22 * e22;

    const float wout0 = wout[0], wout1 = wout[1];
    const float cref  = g_tab[32];
    const char* W1c  = (const char*)W1;
    const char* b1c  = (const char*)b1;
    const char* Wc0c = (const char*)Wc0;
    const char* bc0c = (const char*)bc0;
    const char* Wc1c = (const char*)Wc1;
    const char* bc1c = (const char*)bc1;
    const char* aoc  = (const char*)&g_tab[0];

    float g0p = 0.0f, gqp = 0.0f;

    // ---- Stage A: z B-frags computed directly (unit j = 16c + 8*hB + b)
    uint zf[2][4];
    #pragma unroll
    for (int c = 0; c < 2; ++c)
    #pragma unroll
    for (int s = 0; s < 4; ++s) {
        const float4v w4 = *(const float4v*)(W1c + 64 * hB + 128 * c + 16 * s);
        const float2v b2 = *(const float2v*)(b1c + 32 * hB + 64 * c + 8 * s);
        float a0 = fmaf(w4.x, x1, fmaf(w4.y, x2, b2.x));
        float a1 = fmaf(w4.z, x1, fmaf(w4.w, x2, b2.y));
        zf[c][s] = cvt_pk_bf16(sp_only(a0), sp_only(a1));
    }
    uint4v zq0, zq1;
    zq0.x = zf[0][0]; zq0.y = zf[0][1]; zq0.z = zf[0][2]; zq0.w = zf[0][3];
    zq1.x = zf[1][0]; zq1.y = zf[1][1]; zq1.z = zf[1][2]; zq1.w = zf[1][3];
    s8b fA = __builtin_bit_cast(s8b, zq0);
    s8b fB = __builtin_bit_cast(s8b, zq1);

    // ---- matvec 0: u0 = A0 z
    f32x16 acc = {};
    MM(0, fA, fB, acc)

    // ---- Stage B epilogue: d0 (packed), zn (packed, exact f32 c0)
    uint pd0[8], pz[8];
    #pragma unroll
    for (int q = 0; q < 8; ++q) {
        const int e = 2 * q, off = OFF(e);
        const float4v wc = *(const float4v*)(Wc0c + 32 * hB + 8 * off);
        const float2v bc = *(const float2v*)(bc0c + 16 * hB + 4 * off);
        float su;  float t  = sp_sig(acc[e], su);
        float su2; float t2 = sp_sig(acc[e + 1], su2);
        float c0a = fmaf(wc.x, x1, fmaf(wc.y, x2, bc.x));
        float c0b = fmaf(wc.z, x1, fmaf(wc.w, x2, bc.y));
        pd0[q] = cvt_pk_bf16(kAct2 * t * su, kAct2 * t2 * su2);
        pz[q]  = cvt_pk_bf16(fmaf(kActScale * t, t, sp_only(c0a)),
                             fmaf(kActScale * t2, t2, sp_only(c0b)));
    }
    SWAPJ(pz, fA, fB)

    // ---- matvec 1: u1 = A1 zn
    f32x16 acc1 = {};
    MM(1, fA, fB, acc1)

    // ---- Stage C: T1 fold (c1-skip) + d1
    uint pdd[8];
    #pragma unroll
    for (int q = 0; q < 8; ++q) {
        const int e = 2 * q, off = OFF(e);
        const float4v wc = *(const float4v*)(Wc1c + 32 * hB + 8 * off);
        const float2v bc = *(const float2v*)(bc1c + 16 * hB + 4 * off);
        const float2v ao = *(const float2v*)(aoc  + 16 * hB + 4 * off);
        float c1a = fmaf(wc.x, x1, fmaf(wc.y, x2, bc.x));
        float c1b = fmaf(wc.z, x1, fmaf(wc.w, x2, bc.y));
        float wA = ao.x * sig_only(c1a);
        float wB = ao.y * sig_only(c1b);
        g0p = fmaf(wc.x, wA, g0p); gqp = fmaf(wc.y, wA, gqp);
        g0p = fmaf(wc.z, wB, g0p); gqp = fmaf(wc.w, wB, gqp);
        float su;  float t  = sp_sig(acc1[e], su);
        float su2; float t2 = sp_sig(acc1[e + 1], su2);
        pdd[q] = cvt_pk_bf16(ao.x * kAct2 * t * su, ao.y * kAct2 * t2 * su2);
    }
    SWAPJ(pdd, fA, fB)

    // ---- matvec 2: g = A1^T d1 (raw f32 in acc2)
    f32x16 acc2 = {};
    MM(2, fA, fB, acc2)

    // ---- T2 fold (c0-skip, reversed assoc) + gg = g*d0
    uint pgg[8];
    #pragma unroll
    for (int q = 0; q < 8; ++q) {
        const int e = 2 * q, off = OFF(e);
        const float4v wc = *(const float4v*)(Wc0c + 32 * hB + 8 * off);
        const float2v bc = *(const float2v*)(bc0c + 16 * hB + 4 * off);
        float c0a = fmaf(wc.y, x2, fmaf(wc.x, x1, bc.x));
        float c0b = fmaf(wc.w, x2, fmaf(wc.z, x1, bc.y));
        float tA = acc2[e]     * sig_only(c0a);
        float tB = acc2[e + 1] * sig_only(c0b);
        g0p = fmaf(wc.x, tA, g0p); gqp = fmaf(wc.y, tA, gqp);
        g0p = fmaf(wc.z, tB, g0p); gqp = fmaf(wc.w, tB, gqp);
        pgg[q] = cvt_pk_bf16(acc2[e] * bf16f(pd0[q] & 0xFFFFu),
                             acc2[e + 1] * bf16f(pd0[q] >> 16));
    }
    SWAPJ(pgg, fA, fB)

    // ---- matvec 3: A0^T gg
    f32x16 acc3 = {};
    MM(3, fA, fB, acc3)

    // ---- T3 fold (first-layer, reversed assoc)
    #pragma unroll
    for (int q = 0; q < 8; ++q) {
        const int e = 2 * q, off = OFF(e);
        const float4v w4 = *(const float4v*)(W1c + 32 * hB + 8 * off);
        const float2v b2 = *(const float2v*)(b1c + 16 * hB + 4 * off);
        float aa = fmaf(w4.y, x2, fmaf(w4.x, x1, b2.x));
        float ab = fmaf(w4.w, x2, fmaf(w4.z, x1, b2.y));
        float gA = acc3[e]     * sig_only(aa);
        float gB = acc3[e + 1] * sig_only(ab);
        g0p = fmaf(w4.x, gA, g0p); gqp = fmaf(w4.y, gA, gqp);
        g0p = fmaf(w4.z, gB, g0p); gqp = fmaf(w4.w, gB, gqp);
    }

    // ---- cross-half reduce; lanes < 32 write their row
    float g0f = wout0 + g0p + __shfl_xor(g0p, 32, 64);
    float gqf = wout1 + gqp + __shfl_xor(gqp, 32, 64);
    const float dI1 = g0f - cref;
    const float dI2 = gqf;
    if (!hb_) {
        out[rowg * 3 + 0] = fmaf(2.0f * e11, dI2, dI1);
        out[rowg * 3 + 1] = fmaf(2.0f * e22, dI2, dI1);
        out[rowg * 3 + 2] = 2.0f * e12 * dI2;
    }
}

extern "C" void kernel_launch(void* const* d_in, const int* in_sizes, int n_in,
                              void* d_out, int out_size, void* d_ws, size_t ws_size,
                              hipStream_t stream)
{
    (void)in_sizes; (void)n_in; (void)out_size; (void)d_ws; (void)ws_size;
    const float* eps    = (const float*)d_in[0];
    const float* W1     = (const float*)d_in[1];
    const float* b1     = (const float*)d_in[2];
    const float* rawA0  = (const float*)d_in[3];
    const float* rawA1  = (const float*)d_in[4];
    const float* Wc0    = (const float*)d_in[5];
    const float* bc0    = (const float*)d_in[6];
    const float* Wc1    = (const float*)d_in[7];
    const float* bc1    = (const float*)d_in[8];
    const float* rawAout= (const float*)d_in[9];
    const float* wout   = (const float*)d_in[10];
    float* out = (float*)d_out;

    icnn_prep<<<1, 256, 0, stream>>>(rawA0, rawA1, rawAout, W1, b1, Wc0, bc0, Wc1, bc1, wout);
    icnn_main<<<kBatch / 128, 256, 0, stream>>>(eps, W1, b1, Wc0, bc0, Wc1, bc1, wout, out);
}

// Round 16
// 258.096 us; speedup vs baseline: 1.8694x; 1.2427x over previous
//
#include <hip/hip_runtime.h>

typedef __attribute__((ext_vector_type(8)))  short s8b;    // 8 x bf16
typedef __attribute__((ext_vector_type(16))) float f32x16; // mfma C/D
typedef __attribute__((ext_vector_type(4)))  uint  uint4v;
typedef __attribute__((ext_vector_type(2)))  float float2v;
typedef __attribute__((ext_vector_type(4)))  float float4v;
typedef uint __attribute__((may_alias)) uint_ma;

static constexpr int   kBatch    = 2097152;
static constexpr float kActScale = 1.0f / 12.0f;
static constexpr float kAct2     = 1.0f / 6.0f;   // 2*ACT_SCALE

// fp32 table: [0,32) aout ; [32] cref
__device__ float g_tab[40];
// Weight A-frag tables, per matvec m: lane l holds W_m[row=l&31][j=16c+8*(l>>5)+b]
// m: 0=A0, 1=A1, 2=A1^T, 3=A0^T ; hl: 0=hi,1=lo ; c: k-chunk
__device__ __attribute__((aligned(16))) ushort g_wt[4][2][2][64][8];

__device__ __forceinline__ float rcp_f(float x) { return __fdividef(1.0f, x); }
__device__ __forceinline__ float sp_only(float x) {
    float e = __expf(-fabsf(x));
    return fmaxf(x, 0.0f) + __logf(1.0f + e);
}
__device__ __forceinline__ float sig_only(float x) {
    float e = __expf(-fabsf(x));
    float r = rcp_f(1.0f + e);
    return (x >= 0.0f) ? r : e * r;
}
__device__ __forceinline__ float sp_sig(float x, float& sig) {
    float e  = __expf(-fabsf(x));
    float oe = 1.0f + e;
    float r  = rcp_f(oe);
    sig = (x >= 0.0f) ? r : e * r;
    return fmaxf(x, 0.0f) + __logf(oe);
}

// ---- trans-diet versions (main kernel only) ----
// log1p(e) on e in (0,1]: A&S 4.1.43 deg-5 minimax, |err| <= 1e-5.
// Replaces v_log (quarter-rate trans) with 5 full-rate FMAs.
__device__ __forceinline__ float log1p_e(float e) {
    return e * fmaf(e, fmaf(e, fmaf(e, fmaf(e, 0.03215845f, -0.13606275f),
                                    0.28947478f), -0.49190896f), 0.99949556f);
}
// softplus + sigmoid sharing one exp, log-free
__device__ __forceinline__ float sp_sig_p(float x, float& sig) {
    float e = __expf(-fabsf(x));
    float r = rcp_f(1.0f + e);
    sig = (x >= 0.0f) ? r : e * r;
    return fmaxf(x, 0.0f) + log1p_e(e);
}

__device__ __forceinline__ uint  bf16u(float x) {
    uint u = __float_as_uint(x);
    return (u + 0x7FFFu + ((u >> 16) & 1u)) >> 16;      // RNE
}
__device__ __forceinline__ float bf16f(uint h) { return __uint_as_float(h << 16); }
__device__ __forceinline__ uint cvt_pk_bf16(float lo, float hi) {
    uint r;
    asm("v_cvt_pk_bf16_f32 %0, %1, %2" : "=v"(r) : "v"(lo), "v"(hi));
    return r;
}

// ---------------- prep: A-frag weight tables + aout + cref -------------------
__global__ __launch_bounds__(256) void icnn_prep(
    const float* __restrict__ rawA0, const float* __restrict__ rawA1,
    const float* __restrict__ rawAout,
    const float* __restrict__ W1,  const float* __restrict__ b1,
    const float* __restrict__ Wc0, const float* __restrict__ bc0,
    const float* __restrict__ Wc1, const float* __restrict__ bc1,
    const float* __restrict__ wout)
{
    __shared__ float sA0[1024], sA1[1024], sAout[32];
    const int t = threadIdx.x;
    for (int k = t; k < 1024; k += 256) sA0[k] = sp_only(rawA0[k]);
    for (int k = t; k < 1024; k += 256) sA1[k] = sp_only(rawA1[k]);
    if (t < 32) { float v = sp_only(rawAout[t]); sAout[t] = v; g_tab[t] = v; }
    __syncthreads();

    // A-frag tables: element (m, hl, c, l, b) = W_m[l&31][16c + 8*(l>>5) + b]
    for (int k = t; k < 8192; k += 256) {
        int m = k >> 11, r = k & 2047;
        int hl = r >> 10, c = (r >> 9) & 1, l = (r >> 3) & 63, b = r & 7;
        int row = l & 31, j = 16 * c + 8 * (l >> 5) + b;
        float v;
        if      (m == 0) v = sA0[row * 32 + j];
        else if (m == 1) v = sA1[row * 32 + j];
        else if (m == 2) v = sA1[j * 32 + row];     // A1^T
        else             v = sA0[j * 32 + row];     // A0^T
        uint hi = bf16u(v);
        g_wt[m][hl][c][l][b] = (ushort)(hl == 0 ? hi : bf16u(v - bf16f(hi)));
    }

    // cref: exact fp32 gradient dW/dI1 at z0 = 0 (wave-0 lanes 0..31)
    if (t < 32) {
        const int i = t;
        float sa, sc0v;
        float zi = sp_sig(b1[i], sa);
        float u = 0.0f;
        for (int j = 0; j < 32; j++) u = fmaf(sA0[i * 32 + j], __shfl(zi, j, 64), u);
        float su; float t0 = sp_sig(u, su);
        float d0 = kAct2 * t0 * su;
        float spc = sp_sig(bc0[i], sc0v);
        float zn = fmaf(kActScale * t0, t0, spc);
        float u1 = 0.0f;
        for (int j = 0; j < 32; j++) u1 = fmaf(sA1[i * 32 + j], __shfl(zn, j, 64), u1);
        float su1; float t1 = sp_sig(u1, su1);
        float d1 = sAout[i] * kAct2 * t1 * su1;
        float contrib = Wc1[2 * i] * sAout[i] * sig_only(bc1[i]);
        float g = 0.0f;
        for (int j = 0; j < 32; j++) g = fmaf(sA1[j * 32 + i], __shfl(d1, j, 64), g);
        contrib = fmaf(Wc0[2 * i], g * sc0v, contrib);
        float gu0 = g * d0;
        float ga = 0.0f;
        for (int j = 0; j < 32; j++) ga = fmaf(sA0[j * 32 + i], __shfl(gu0, j, 64), ga);
        ga *= sa;
        contrib = fmaf(W1[2 * i], ga, contrib);
        for (int off = 16; off >= 1; off >>= 1)
            contrib += __shfl_down(contrib, off, 32);
        if (i == 0) g_tab[32] = wout[0] + contrib;
    }
}

// weight A-frag load (pure SSA, 16B aligned)
__device__ __forceinline__ s8b ldwt(int m, int hl, int c, int lane) {
    const uint_ma* p = (const uint_ma*)&g_wt[m][hl][c][lane][0];
    uint4v q; q.x = p[0]; q.y = p[1]; q.z = p[2]; q.w = p[3];
    return __builtin_bit_cast(s8b, q);
}

// i-offset of C-frag element e (i = 4*half + OFF(e))
#define OFF(e) (((e) & 3) + 8 * ((e) >> 2))

// cross-half exchange: packed pair dwords PZ[0..7] (PZ[q] = units (4h+OFF(2q), +1))
// -> B-frags FA (k=0..15) and FB (k=16..31)
#define SXU(v) ((uint)__shfl_xor((int)(v), 32, 64))
#define SWAPJ(PZ, FA, FB) { \
    uint a0 = SXU(PZ[0]), a1 = SXU(PZ[1]), a2 = SXU(PZ[2]), a3 = SXU(PZ[3]); \
    uint a4 = SXU(PZ[4]), a5 = SXU(PZ[5]), a6 = SXU(PZ[6]), a7 = SXU(PZ[7]); \
    uint4v qa, qb; \
    qa.x = hb_ ? a2 : PZ[0]; qa.y = hb_ ? a3 : PZ[1]; \
    qa.z = hb_ ? PZ[2] : a0; qa.w = hb_ ? PZ[3] : a1; \
    qb.x = hb_ ? a6 : PZ[4]; qb.y = hb_ ? a7 : PZ[5]; \
    qb.z = hb_ ? PZ[6] : a4; qb.w = hb_ ? PZ[7] : a5; \
    FA = __builtin_bit_cast(s8b, qa); FB = __builtin_bit_cast(s8b, qb); }

// 4-mfma matvec: acc += (Whi + Wlo) x B, K=32 via 2 chained chunks
#define MM(m, BA, BB, ACC) { \
    ACC = __builtin_amdgcn_mfma_f32_32x32x16_bf16(ldwt(m, 0, 0, lane), BA, ACC, 0, 0, 0); \
    ACC = __builtin_amdgcn_mfma_f32_32x32x16_bf16(ldwt(m, 0, 1, lane), BB, ACC, 0, 0, 0); \
    ACC = __builtin_amdgcn_mfma_f32_32x32x16_bf16(ldwt(m, 1, 0, lane), BA, ACC, 0, 0, 0); \
    ACC = __builtin_amdgcn_mfma_f32_32x32x16_bf16(ldwt(m, 1, 1, lane), BB, ACC, 0, 0, 0); }

// ---------------- main: weights-as-A MFMA, one 32-row tile/wave --------------
// R15 base + transcendental diet: (a) log-free softplus (deg-5 poly),
// (b) sigma(a)/sigma(c0) computed where 1+e already exists (stages A/B),
// packed bf16 and carried through conflict-free LDS scratch to T3/T2
// (stride-17 dwords; same-wave DS ordering, no barriers). 256 -> 160 trans.
__global__ __launch_bounds__(256) void icnn_main(
    const float* __restrict__ eps,
    const float* __restrict__ W1,  const float* __restrict__ b1,
    const float* __restrict__ Wc0, const float* __restrict__ bc0,
    const float* __restrict__ Wc1, const float* __restrict__ bc1,
    const float* __restrict__ wout,
    float* __restrict__ out)
{
    __shared__ uint carr[4][2][544];              // 17408 B: [wave][sigA|sigC0]
    const int tid  = threadIdx.x;
    const int lane = tid & 63, wib = tid >> 6;
    const bool hb_ = lane >= 32;
    const int  hB  = hb_ ? 1 : 0;
    const int  rowl = lane & 31;
    const long rowg = ((long)blockIdx.x * 4 + wib) * 32 + rowl;
    uint* __restrict__ ca = &carr[wib][0][0];     // sigma(a)
    uint* __restrict__ cc = &carr[wib][1][0];     // sigma(c0)

    const float e11 = eps[rowg * 3 + 0];
    const float e22 = eps[rowg * 3 + 1];
    const float e12 = eps[rowg * 3 + 2];
    const float x1 = e11 + e22;
    const float x2 = e11 * e11 + 2.0f * e12 * e12 + e22 * e22;

    const float wout0 = wout[0], wout1 = wout[1];
    const float cref  = g_tab[32];
    const char* W1c  = (const char*)W1;
    const char* b1c  = (const char*)b1;
    const char* Wc0c = (const char*)Wc0;
    const char* bc0c = (const char*)bc0;
    const char* Wc1c = (const char*)Wc1;
    const char* bc1c = (const char*)bc1;
    const char* aoc  = (const char*)&g_tab[0];

    float g0p = 0.0f, gqp = 0.0f;

    // ---- Stage A: z = sp(a) B-frags (unit j = 16c + 8*hB + 2s,2s+1);
    //      sigma(a) -> LDS carry (unit-pair dword at row*17 + 8c + 4hB + s)
    uint zf[2][4];
    #pragma unroll
    for (int c = 0; c < 2; ++c)
    #pragma unroll
    for (int s = 0; s < 4; ++s) {
        const float4v w4 = *(const float4v*)(W1c + 64 * hB + 128 * c + 16 * s);
        const float2v b2 = *(const float2v*)(b1c + 32 * hB + 64 * c + 8 * s);
        float a0 = fmaf(w4.x, x1, fmaf(w4.y, x2, b2.x));
        float a1 = fmaf(w4.z, x1, fmaf(w4.w, x2, b2.y));
        float s0, s1;
        float z0 = sp_sig_p(a0, s0);
        float z1 = sp_sig_p(a1, s1);
        zf[c][s] = cvt_pk_bf16(z0, z1);
        ca[rowl * 17 + 8 * c + 4 * hB + s] = cvt_pk_bf16(s0, s1);
    }
    uint4v zq0, zq1;
    zq0.x = zf[0][0]; zq0.y = zf[0][1]; zq0.z = zf[0][2]; zq0.w = zf[0][3];
    zq1.x = zf[1][0]; zq1.y = zf[1][1]; zq1.z = zf[1][2]; zq1.w = zf[1][3];
    s8b fA = __builtin_bit_cast(s8b, zq0);
    s8b fB = __builtin_bit_cast(s8b, zq1);

    // ---- matvec 0: u0 = A0 z
    f32x16 acc = {};
    MM(0, fA, fB, acc)

    // ---- Stage B epilogue: d0, zn; sigma(c0) -> LDS carry
    uint pd0[8], pz[8];
    #pragma unroll
    for (int q = 0; q < 8; ++q) {
        const int e = 2 * q, off = OFF(e);
        const float4v wc = *(const float4v*)(Wc0c + 32 * hB + 8 * off);
        const float2v bc = *(const float2v*)(bc0c + 16 * hB + 4 * off);
        float su;  float t  = sp_sig_p(acc[e], su);
        float su2; float t2 = sp_sig_p(acc[e + 1], su2);
        float c0a = fmaf(wc.x, x1, fmaf(wc.y, x2, bc.x));
        float c0b = fmaf(wc.z, x1, fmaf(wc.w, x2, bc.y));
        float sc0, sc1;
        float spc0 = sp_sig_p(c0a, sc0);
        float spc1 = sp_sig_p(c0b, sc1);
        cc[rowl * 17 + 2 * hB + (off >> 1)] = cvt_pk_bf16(sc0, sc1);
        pd0[q] = cvt_pk_bf16(kAct2 * t * su, kAct2 * t2 * su2);
        pz[q]  = cvt_pk_bf16(fmaf(kActScale * t, t, spc0),
                             fmaf(kActScale * t2, t2, spc1));
    }
    SWAPJ(pz, fA, fB)

    // ---- matvec 1: u1 = A1 zn
    f32x16 acc1 = {};
    MM(1, fA, fB, acc1)

    // ---- Stage C: T1 fold (c1-skip) + d1
    uint pdd[8];
    #pragma unroll
    for (int q = 0; q < 8; ++q) {
        const int e = 2 * q, off = OFF(e);
        const float4v wc = *(const float4v*)(Wc1c + 32 * hB + 8 * off);
        const float2v bc = *(const float2v*)(bc1c + 16 * hB + 4 * off);
        const float2v ao = *(const float2v*)(aoc  + 16 * hB + 4 * off);
        float c1a = fmaf(wc.x, x1, fmaf(wc.y, x2, bc.x));
        float c1b = fmaf(wc.z, x1, fmaf(wc.w, x2, bc.y));
        float wA = ao.x * sig_only(c1a);
        float wB = ao.y * sig_only(c1b);
        g0p = fmaf(wc.x, wA, g0p); gqp = fmaf(wc.y, wA, gqp);
        g0p = fmaf(wc.z, wB, g0p); gqp = fmaf(wc.w, wB, gqp);
        float su;  float t  = sp_sig_p(acc1[e], su);
        float su2; float t2 = sp_sig_p(acc1[e + 1], su2);
        pdd[q] = cvt_pk_bf16(ao.x * kAct2 * t * su, ao.y * kAct2 * t2 * su2);
    }
    SWAPJ(pdd, fA, fB)

    // ---- matvec 2: g = A1^T d1 (raw f32 in acc2)
    f32x16 acc2 = {};
    MM(2, fA, fB, acc2)

    // ---- T2 fold: sigma(c0) from LDS carry (no exp/rcp) + gg = g*d0
    uint pgg[8];
    #pragma unroll
    for (int q = 0; q < 8; ++q) {
        const int e = 2 * q, off = OFF(e);
        const float4v wc = *(const float4v*)(Wc0c + 32 * hB + 8 * off);
        uint pk = cc[rowl * 17 + 2 * hB + (off >> 1)];
        float tA = acc2[e]     * bf16f(pk & 0xFFFFu);
        float tB = acc2[e + 1] * bf16f(pk >> 16);
        g0p = fmaf(wc.x, tA, g0p); gqp = fmaf(wc.y, tA, gqp);
        g0p = fmaf(wc.z, tB, g0p); gqp = fmaf(wc.w, tB, gqp);
        pgg[q] = cvt_pk_bf16(acc2[e] * bf16f(pd0[q] & 0xFFFFu),
                             acc2[e + 1] * bf16f(pd0[q] >> 16));
    }
    SWAPJ(pgg, fA, fB)

    // ---- matvec 3: A0^T gg
    f32x16 acc3 = {};
    MM(3, fA, fB, acc3)

    // ---- T3 fold: sigma(a) from LDS carry (no exp/rcp)
    #pragma unroll
    for (int q = 0; q < 8; ++q) {
        const int e = 2 * q, off = OFF(e);
        const float4v w4 = *(const float4v*)(W1c + 32 * hB + 8 * off);
        uint pk = ca[rowl * 17 + 2 * hB + (off >> 1)];
        float gA = acc3[e]     * bf16f(pk & 0xFFFFu);
        float gB = acc3[e + 1] * bf16f(pk >> 16);
        g0p = fmaf(w4.x, gA, g0p); gqp = fmaf(w4.y, gA, gqp);
        g0p = fmaf(w4.z, gB, g0p); gqp = fmaf(w4.w, gB, gqp);
    }

    // ---- cross-half reduce; lanes < 32 write their row
    float g0f = wout0 + g0p + __shfl_xor(g0p, 32, 64);
    float gqf = wout1 + gqp + __shfl_xor(gqp, 32, 64);
    const float dI1 = g0f - cref;
    const float dI2 = gqf;
    if (!hb_) {
        out[rowg * 3 + 0] = fmaf(2.0f * e11, dI2, dI1);
        out[rowg * 3 + 1] = fmaf(2.0f * e22, dI2, dI1);
        out[rowg * 3 + 2] = 2.0f * e12 * dI2;
    }
}

extern "C" void kernel_launch(void* const* d_in, const int* in_sizes, int n_in,
                              void* d_out, int out_size, void* d_ws, size_t ws_size,
                              hipStream_t stream)
{
    (void)in_sizes; (void)n_in; (void)out_size; (void)d_ws; (void)ws_size;
    const float* eps    = (const float*)d_in[0];
    const float* W1     = (const float*)d_in[1];
    const float* b1     = (const float*)d_in[2];
    const float* rawA0  = (const float*)d_in[3];
    const float* rawA1  = (const float*)d_in[4];
    const float* Wc0    = (const float*)d_in[5];
    const float* bc0    = (const float*)d_in[6];
    const float* Wc1    = (const float*)d_in[7];
    const float* bc1    = (const float*)d_in[8];
    const float* rawAout= (const float*)d_in[9];
    const float* wout   = (const float*)d_in[10];
    float* out = (float*)d_out;

    icnn_prep<<<1, 256, 0, stream>>>(rawA0, rawA1, rawAout, W1, b1, Wc0, bc0, Wc1, bc1, wout);
    icnn_main<<<kBatch / 128, 256, 0, stream>>>(eps, W1, b1, Wc0, bc0, Wc1, bc1, wout, out);
}

// Round 17
// 185.522 us; speedup vs baseline: 2.6007x; 1.3912x over previous
//
#include <hip/hip_runtime.h>

typedef __attribute__((ext_vector_type(8)))  short s8b;    // 8 x bf16
typedef __attribute__((ext_vector_type(16))) float f32x16; // mfma C/D
typedef __attribute__((ext_vector_type(4)))  uint  uint4v;
typedef __attribute__((ext_vector_type(2)))  float float2v;
typedef __attribute__((ext_vector_type(4)))  float float4v;
typedef uint __attribute__((may_alias)) uint_ma;

static constexpr int   kBatch    = 2097152;
static constexpr float kActScale = 1.0f / 12.0f;
static constexpr float kAct2     = 1.0f / 6.0f;   // 2*ACT_SCALE

// fp32 table: [0,32) aout ; [32] cref
__device__ float g_tab[40];
// Weight A-frag tables, per matvec m: lane l holds W_m[row=l&31][j=16c+8*(l>>5)+b]
// m: 0=A0, 1=A1, 2=A1^T, 3=A0^T ; hl: 0=hi,1=lo ; c: k-chunk
__device__ __attribute__((aligned(16))) ushort g_wt[4][2][2][64][8];

__device__ __forceinline__ float rcp_f(float x) { return __fdividef(1.0f, x); }
__device__ __forceinline__ float sp_only(float x) {
    float e = __expf(-fabsf(x));
    return fmaxf(x, 0.0f) + __logf(1.0f + e);
}
__device__ __forceinline__ float sig_only(float x) {
    float e = __expf(-fabsf(x));
    float r = rcp_f(1.0f + e);
    return (x >= 0.0f) ? r : e * r;
}
__device__ __forceinline__ float sp_sig(float x, float& sig) {
    float e  = __expf(-fabsf(x));
    float oe = 1.0f + e;
    float r  = rcp_f(oe);
    sig = (x >= 0.0f) ? r : e * r;
    return fmaxf(x, 0.0f) + __logf(oe);
}

// ---- trans-diet versions (main kernel only) ----
// log1p(e) on e in (0,1]: deg-5 minimax, |err| <= 1e-5. 5 full-rate FMAs.
__device__ __forceinline__ float log1p_e(float e) {
    return e * fmaf(e, fmaf(e, fmaf(e, fmaf(e, 0.03215845f, -0.13606275f),
                                    0.28947478f), -0.49190896f), 0.99949556f);
}
// 1/u on u in [1,2] (u = 1+e): linear minimax seed + 2 Newton steps.
// rel err ~1.3e-5, 5 full-rate ops, NO v_rcp.
__device__ __forceinline__ float rcp12(float u) {
    float r = fmaf(u, -0.5f, 1.4571068f);
    r = r * fmaf(-u, r, 2.0f);
    r = r * fmaf(-u, r, 2.0f);
    return r;
}
// general softplus+sigmoid: 1 exp, rest full-rate
__device__ __forceinline__ float sp_sig_p(float x, float& sig) {
    float e = __expf(-fabsf(x));
    float r = rcp12(1.0f + e);
    sig = (x >= 0.0f) ? r : e * r;
    return fmaxf(x, 0.0f) + log1p_e(e);
}
// x >= 0 guaranteed (u0, u1 are sums of positive products)
__device__ __forceinline__ float sp_sig_pos(float x, float& sig) {
    float e = __expf(-x);
    sig = rcp12(1.0f + e);
    return x + log1p_e(e);
}
__device__ __forceinline__ float sig_only_p(float x) {
    float e = __expf(-fabsf(x));
    float r = rcp12(1.0f + e);
    return (x >= 0.0f) ? r : e * r;
}

__device__ __forceinline__ uint  bf16u(float x) {
    uint u = __float_as_uint(x);
    return (u + 0x7FFFu + ((u >> 16) & 1u)) >> 16;      // RNE
}
__device__ __forceinline__ float bf16f(uint h) { return __uint_as_float(h << 16); }
__device__ __forceinline__ uint cvt_pk_bf16(float lo, float hi) {
    uint r;
    asm("v_cvt_pk_bf16_f32 %0, %1, %2" : "=v"(r) : "v"(lo), "v"(hi));
    return r;
}
// cross-half exchange primitive (VALU pipe, replaces ds_bpermute shfl_xor32):
// newA = {A[0..31], B[0..31]}, newB = {A[32..63], B[32..63]}
__device__ __forceinline__ void pswap(uint& a, uint& b) {
    asm("v_permlane32_swap_b32 %0, %1" : "+v"(a), "+v"(b));
}

// ---------------- prep: A-frag weight tables + aout + cref -------------------
__global__ __launch_bounds__(256) void icnn_prep(
    const float* __restrict__ rawA0, const float* __restrict__ rawA1,
    const float* __restrict__ rawAout,
    const float* __restrict__ W1,  const float* __restrict__ b1,
    const float* __restrict__ Wc0, const float* __restrict__ bc0,
    const float* __restrict__ Wc1, const float* __restrict__ bc1,
    const float* __restrict__ wout)
{
    __shared__ float sA0[1024], sA1[1024], sAout[32];
    const int t = threadIdx.x;
    for (int k = t; k < 1024; k += 256) sA0[k] = sp_only(rawA0[k]);
    for (int k = t; k < 1024; k += 256) sA1[k] = sp_only(rawA1[k]);
    if (t < 32) { float v = sp_only(rawAout[t]); sAout[t] = v; g_tab[t] = v; }
    __syncthreads();

    // A-frag tables: element (m, hl, c, l, b) = W_m[l&31][16c + 8*(l>>5) + b]
    for (int k = t; k < 8192; k += 256) {
        int m = k >> 11, r = k & 2047;
        int hl = r >> 10, c = (r >> 9) & 1, l = (r >> 3) & 63, b = r & 7;
        int row = l & 31, j = 16 * c + 8 * (l >> 5) + b;
        float v;
        if      (m == 0) v = sA0[row * 32 + j];
        else if (m == 1) v = sA1[row * 32 + j];
        else if (m == 2) v = sA1[j * 32 + row];     // A1^T
        else             v = sA0[j * 32 + row];     // A0^T
        uint hi = bf16u(v);
        g_wt[m][hl][c][l][b] = (ushort)(hl == 0 ? hi : bf16u(v - bf16f(hi)));
    }

    // cref: exact fp32 gradient dW/dI1 at z0 = 0 (wave-0 lanes 0..31)
    if (t < 32) {
        const int i = t;
        float sa, sc0v;
        float zi = sp_sig(b1[i], sa);
        float u = 0.0f;
        for (int j = 0; j < 32; j++) u = fmaf(sA0[i * 32 + j], __shfl(zi, j, 64), u);
        float su; float t0 = sp_sig(u, su);
        float d0 = kAct2 * t0 * su;
        float spc = sp_sig(bc0[i], sc0v);
        float zn = fmaf(kActScale * t0, t0, spc);
        float u1 = 0.0f;
        for (int j = 0; j < 32; j++) u1 = fmaf(sA1[i * 32 + j], __shfl(zn, j, 64), u1);
        float su1; float t1 = sp_sig(u1, su1);
        float d1 = sAout[i] * kAct2 * t1 * su1;
        float contrib = Wc1[2 * i] * sAout[i] * sig_only(bc1[i]);
        float g = 0.0f;
        for (int j = 0; j < 32; j++) g = fmaf(sA1[j * 32 + i], __shfl(d1, j, 64), g);
        contrib = fmaf(Wc0[2 * i], g * sc0v, contrib);
        float gu0 = g * d0;
        float ga = 0.0f;
        for (int j = 0; j < 32; j++) ga = fmaf(sA0[j * 32 + i], __shfl(gu0, j, 64), ga);
        ga *= sa;
        contrib = fmaf(W1[2 * i], ga, contrib);
        for (int off = 16; off >= 1; off >>= 1)
            contrib += __shfl_down(contrib, off, 32);
        if (i == 0) g_tab[32] = wout[0] + contrib;
    }
}

// weight A-frag load (pure SSA, 16B aligned)
__device__ __forceinline__ s8b ldwt(int m, int hl, int c, int lane) {
    const uint_ma* p = (const uint_ma*)&g_wt[m][hl][c][lane][0];
    uint4v q; q.x = p[0]; q.y = p[1]; q.z = p[2]; q.w = p[3];
    return __builtin_bit_cast(s8b, q);
}

// i-offset of C-frag element e (i = 4*half + OFF(e))
#define OFF(e) (((e) & 3) + 8 * ((e) >> 2))

// cross-half exchange via permlane32_swap: 4 VALU ops replace 8 ds_bpermute
// + 8 cndmask. After pswap(PZ0,PZ2): PZ0 = {h0:(0,1) | h1:(8,9)} etc --
// exactly the B-frag dword each half needs (verified mapping, R17 notes).
#define SWAPJ(PZ, FA, FB) { \
    uint s0 = PZ[0], s1 = PZ[1], s2 = PZ[2], s3 = PZ[3]; \
    uint s4 = PZ[4], s5 = PZ[5], s6 = PZ[6], s7 = PZ[7]; \
    pswap(s0, s2); pswap(s1, s3); pswap(s4, s6); pswap(s5, s7); \
    uint4v qa, qb; \
    qa.x = s0; qa.y = s1; qa.z = s2; qa.w = s3; \
    qb.x = s4; qb.y = s5; qb.z = s6; qb.w = s7; \
    FA = __builtin_bit_cast(s8b, qa); FB = __builtin_bit_cast(s8b, qb); }

// 4-mfma matvec: acc += (Whi + Wlo) x B, K=32 via 2 chained chunks
#define MM(m, BA, BB, ACC) { \
    ACC = __builtin_amdgcn_mfma_f32_32x32x16_bf16(ldwt(m, 0, 0, lane), BA, ACC, 0, 0, 0); \
    ACC = __builtin_amdgcn_mfma_f32_32x32x16_bf16(ldwt(m, 0, 1, lane), BB, ACC, 0, 0, 0); \
    ACC = __builtin_amdgcn_mfma_f32_32x32x16_bf16(ldwt(m, 1, 0, lane), BA, ACC, 0, 0, 0); \
    ACC = __builtin_amdgcn_mfma_f32_32x32x16_bf16(ldwt(m, 1, 1, lane), BB, ACC, 0, 0, 0); }

// ---------------- main: weights-as-A MFMA, one 32-row tile/wave --------------
// R16 base + rcp-free sigmoid (Newton poly), positivity-specialized u0/u1
// activations, and permlane32_swap junctions (no ds_bpermute).
__global__ __launch_bounds__(256) void icnn_main(
    const float* __restrict__ eps,
    const float* __restrict__ W1,  const float* __restrict__ b1,
    const float* __restrict__ Wc0, const float* __restrict__ bc0,
    const float* __restrict__ Wc1, const float* __restrict__ bc1,
    const float* __restrict__ wout,
    float* __restrict__ out)
{
    __shared__ uint carr[4][2][544];              // 17408 B: [wave][sigA|sigC0]
    const int tid  = threadIdx.x;
    const int lane = tid & 63, wib = tid >> 6;
    const bool hb_ = lane >= 32;
    const int  hB  = hb_ ? 1 : 0;
    const int  rowl = lane & 31;
    const long rowg = ((long)blockIdx.x * 4 + wib) * 32 + rowl;
    uint* __restrict__ ca = &carr[wib][0][0];     // sigma(a)
    uint* __restrict__ cc = &carr[wib][1][0];     // sigma(c0)

    const float e11 = eps[rowg * 3 + 0];
    const float e22 = eps[rowg * 3 + 1];
    const float e12 = eps[rowg * 3 + 2];
    const float x1 = e11 + e22;
    const float x2 = e11 * e11 + 2.0f * e12 * e12 + e22 * e22;

    const float wout0 = wout[0], wout1 = wout[1];
    const float cref  = g_tab[32];
    const char* W1c  = (const char*)W1;
    const char* b1c  = (const char*)b1;
    const char* Wc0c = (const char*)Wc0;
    const char* bc0c = (const char*)bc0;
    const char* Wc1c = (const char*)Wc1;
    const char* bc1c = (const char*)bc1;
    const char* aoc  = (const char*)&g_tab[0];

    float g0p = 0.0f, gqp = 0.0f;

    // ---- Stage A: z = sp(a) B-frags (unit j = 16c + 8*hB + 2s,2s+1);
    //      sigma(a) -> LDS carry
    uint zf[2][4];
    #pragma unroll
    for (int c = 0; c < 2; ++c)
    #pragma unroll
    for (int s = 0; s < 4; ++s) {
        const float4v w4 = *(const float4v*)(W1c + 64 * hB + 128 * c + 16 * s);
        const float2v b2 = *(const float2v*)(b1c + 32 * hB + 64 * c + 8 * s);
        float a0 = fmaf(w4.x, x1, fmaf(w4.y, x2, b2.x));
        float a1 = fmaf(w4.z, x1, fmaf(w4.w, x2, b2.y));
        float s0, s1;
        float z0 = sp_sig_p(a0, s0);
        float z1 = sp_sig_p(a1, s1);
        zf[c][s] = cvt_pk_bf16(z0, z1);
        ca[rowl * 17 + 8 * c + 4 * hB + s] = cvt_pk_bf16(s0, s1);
    }
    uint4v zq0, zq1;
    zq0.x = zf[0][0]; zq0.y = zf[0][1]; zq0.z = zf[0][2]; zq0.w = zf[0][3];
    zq1.x = zf[1][0]; zq1.y = zf[1][1]; zq1.z = zf[1][2]; zq1.w = zf[1][3];
    s8b fA = __builtin_bit_cast(s8b, zq0);
    s8b fB = __builtin_bit_cast(s8b, zq1);

    // ---- matvec 0: u0 = A0 z
    f32x16 acc = {};
    MM(0, fA, fB, acc)

    // ---- Stage B epilogue: d0, zn; sigma(c0) -> LDS carry (u0 >= 0)
    uint pd0[8], pz[8];
    #pragma unroll
    for (int q = 0; q < 8; ++q) {
        const int e = 2 * q, off = OFF(e);
        const float4v wc = *(const float4v*)(Wc0c + 32 * hB + 8 * off);
        const float2v bc = *(const float2v*)(bc0c + 16 * hB + 4 * off);
        float su;  float t  = sp_sig_pos(acc[e], su);
        float su2; float t2 = sp_sig_pos(acc[e + 1], su2);
        float c0a = fmaf(wc.x, x1, fmaf(wc.y, x2, bc.x));
        float c0b = fmaf(wc.z, x1, fmaf(wc.w, x2, bc.y));
        float sc0, sc1;
        float spc0 = sp_sig_p(c0a, sc0);
        float spc1 = sp_sig_p(c0b, sc1);
        cc[rowl * 17 + 2 * hB + (off >> 1)] = cvt_pk_bf16(sc0, sc1);
        pd0[q] = cvt_pk_bf16(kAct2 * t * su, kAct2 * t2 * su2);
        pz[q]  = cvt_pk_bf16(fmaf(kActScale * t, t, spc0),
                             fmaf(kActScale * t2, t2, spc1));
    }
    SWAPJ(pz, fA, fB)

    // ---- matvec 1: u1 = A1 zn
    f32x16 acc1 = {};
    MM(1, fA, fB, acc1)

    // ---- Stage C: T1 fold (c1-skip) + d1 (u1 >= 0)
    uint pdd[8];
    #pragma unroll
    for (int q = 0; q < 8; ++q) {
        const int e = 2 * q, off = OFF(e);
        const float4v wc = *(const float4v*)(Wc1c + 32 * hB + 8 * off);
        const float2v bc = *(const float2v*)(bc1c + 16 * hB + 4 * off);
        const float2v ao = *(const float2v*)(aoc  + 16 * hB + 4 * off);
        float c1a = fmaf(wc.x, x1, fmaf(wc.y, x2, bc.x));
        float c1b = fmaf(wc.z, x1, fmaf(wc.w, x2, bc.y));
        float wA = ao.x * sig_only_p(c1a);
        float wB = ao.y * sig_only_p(c1b);
        g0p = fmaf(wc.x, wA, g0p); gqp = fmaf(wc.y, wA, gqp);
        g0p = fmaf(wc.z, wB, g0p); gqp = fmaf(wc.w, wB, gqp);
        float su;  float t  = sp_sig_pos(acc1[e], su);
        float su2; float t2 = sp_sig_pos(acc1[e + 1], su2);
        pdd[q] = cvt_pk_bf16(ao.x * kAct2 * t * su, ao.y * kAct2 * t2 * su2);
    }
    SWAPJ(pdd, fA, fB)

    // ---- matvec 2: g = A1^T d1 (raw f32 in acc2)
    f32x16 acc2 = {};
    MM(2, fA, fB, acc2)

    // ---- T2 fold: sigma(c0) from LDS carry + gg = g*d0
    uint pgg[8];
    #pragma unroll
    for (int q = 0; q < 8; ++q) {
        const int e = 2 * q, off = OFF(e);
        const float4v wc = *(const float4v*)(Wc0c + 32 * hB + 8 * off);
        uint pk = cc[rowl * 17 + 2 * hB + (off >> 1)];
        float tA = acc2[e]     * bf16f(pk & 0xFFFFu);
        float tB = acc2[e + 1] * bf16f(pk >> 16);
        g0p = fmaf(wc.x, tA, g0p); gqp = fmaf(wc.y, tA, gqp);
        g0p = fmaf(wc.z, tB, g0p); gqp = fmaf(wc.w, tB, gqp);
        pgg[q] = cvt_pk_bf16(acc2[e] * bf16f(pd0[q] & 0xFFFFu),
                             acc2[e + 1] * bf16f(pd0[q] >> 16));
    }
    SWAPJ(pgg, fA, fB)

    // ---- matvec 3: A0^T gg
    f32x16 acc3 = {};
    MM(3, fA, fB, acc3)

    // ---- T3 fold: sigma(a) from LDS carry
    #pragma unroll
    for (int q = 0; q < 8; ++q) {
        const int e = 2 * q, off = OFF(e);
        const float4v w4 = *(const float4v*)(W1c + 32 * hB + 8 * off);
        uint pk = ca[rowl * 17 + 2 * hB + (off >> 1)];
        float gA = acc3[e]     * bf16f(pk & 0xFFFFu);
        float gB = acc3[e + 1] * bf16f(pk >> 16);
        g0p = fmaf(w4.x, gA, g0p); gqp = fmaf(w4.y, gA, gqp);
        g0p = fmaf(w4.z, gB, g0p); gqp = fmaf(w4.w, gB, gqp);
    }

    // ---- cross-half reduce via permlane32_swap; lanes < 32 write their row
    uint ga_ = __float_as_uint(g0p), gb_ = ga_;
    pswap(ga_, gb_);
    float g0o = __uint_as_float(hb_ ? ga_ : gb_);
    uint qa_ = __float_as_uint(gqp), qb_ = qa_;
    pswap(qa_, qb_);
    float gqo = __uint_as_float(hb_ ? qa_ : qb_);

    float g0f = wout0 + g0p + g0o;
    float gqf = wout1 + gqp + gqo;
    const float dI1 = g0f - cref;
    const float dI2 = gqf;
    if (!hb_) {
        out[rowg * 3 + 0] = fmaf(2.0f * e11, dI2, dI1);
        out[rowg * 3 + 1] = fmaf(2.0f * e22, dI2, dI1);
        out[rowg * 3 + 2] = 2.0f * e12 * dI2;
    }
}

extern "C" void kernel_launch(void* const* d_in, const int* in_sizes, int n_in,
                              void* d_out, int out_size, void* d_ws, size_t ws_size,
                              hipStream_t stream)
{
    (void)in_sizes; (void)n_in; (void)out_size; (void)d_ws; (void)ws_size;
    const float* eps    = (const float*)d_in[0];
    const float* W1     = (const float*)d_in[1];
    const float* b1     = (const float*)d_in[2];
    const float* rawA0  = (const float*)d_in[3];
    const float* rawA1  = (const float*)d_in[4];
    const float* Wc0    = (const float*)d_in[5];
    const float* bc0    = (const float*)d_in[6];
    const float* Wc1    = (const float*)d_in[7];
    const float* bc1    = (const float*)d_in[8];
    const float* rawAout= (const float*)d_in[9];
    const float* wout   = (const float*)d_in[10];
    float* out = (float*)d_out;

    icnn_prep<<<1, 256, 0, stream>>>(rawA0, rawA1, rawAout, W1, b1, Wc0, bc0, Wc1, bc1, wout);
    icnn_main<<<kBatch / 128, 256, 0, stream>>>(eps, W1, b1, Wc0, bc0, Wc1, bc1, wout, out);
}